// Round 4
// baseline (453.827 us; speedup 1.0000x reference)
//
#include <hip/hip_runtime.h>

#define NN 50000
#define EE 800000
#define NBX 391          // ceil(50000/128) row-blocks for gemm
#define NB_FILL 1563     // ceil(400000/256) fill blocks (2 edges/thread)

typedef unsigned short u16;

// ---------------- degree count (2 edges/thread) ----------------
__global__ void k_count(const int* __restrict__ ei, int* cnt) {
    int t = blockIdx.x * 256 + threadIdx.x;
    if (t < EE / 2) {
        int2 cc = *(const int2*)(ei + EE + 2 * t);
        atomicAdd(&cnt[cc.x], 1);
        atomicAdd(&cnt[cc.y], 1);
    }
}

// ---------------- scan pass 1: per-block exclusive scan + dis ----------------
__global__ void k_scan1(const int* __restrict__ cnt, int* sloc, int* bsum,
                        float* dis, int n) {
    __shared__ int s[256];
    int tid = threadIdx.x;
    int i = blockIdx.x * 256 + tid;
    int v = (i < n) ? cnt[i] : 0;
    if (i < n) dis[i] = rsqrtf((float)v + 1.0f);  // +1 self loop
    s[tid] = v;
    __syncthreads();
    for (int off = 1; off < 256; off <<= 1) {
        int t2 = 0;
        if (tid >= off) t2 = s[tid - off];
        __syncthreads();
        if (tid >= off) s[tid] += t2;
        __syncthreads();
    }
    if (i < n) sloc[i] = s[tid] - v;
    if (tid == 255) bsum[blockIdx.x] = s[255];
}

// ---------------- scan pass 2+3 fused: block offset (redundant reduce) + finalize ----------------
__global__ void k_scan23(const int* __restrict__ sloc, const int* __restrict__ bsum,
                         const int* __restrict__ cnt, int2* sd, int* cursor,
                         int n, int nb) {
    __shared__ int sb[256];
    int tid = threadIdx.x, b = blockIdx.x;
    int v = (tid < nb && tid < b) ? bsum[tid] : 0;
    sb[tid] = v;
    __syncthreads();
    for (int off = 128; off; off >>= 1) {
        if (tid < off) sb[tid] += sb[tid + off];
        __syncthreads();
    }
    int boff = sb[0];
    int i = b * 256 + tid;
    if (i < n) {
        int st = sloc[i] + boff;
        sd[i] = make_int2(st, cnt[i]);
        cursor[i] = st;
    }
}

// ---------------- GEMM body: K-split x2, LDS reduce; grp 0,1 -> bases*dis ; 2 -> wcomb ----------------
__device__ __forceinline__ void gemm_body(
    int bx, int grp, int tid,
    const float* __restrict__ x, const float* __restrict__ Wb,
    const float* __restrict__ Wc, const float* __restrict__ bc,
    const float* __restrict__ dis,
    float* __restrict__ bases, float* __restrict__ wcomb,
    float* red, int n)
{
    int rl = tid & 127, kh = tid >> 7;
    int row = bx * 128 + rl;
    bool valid = row < n;
    float acc[32];
#pragma unroll
    for (int c = 0; c < 32; c++) acc[c] = 0.f;

    const float* W = (grp < 2) ? (Wb + grp * 32) : Wc;
    int ldw = (grp < 2) ? 64 : 32;
    const float* Wh = W + kh * 64 * ldw;

    if (valid) {
        const float4* xr = (const float4*)(x + (size_t)row * 128 + kh * 64);
        for (int k4 = 0; k4 < 16; k4++) {
            float4 xv = xr[k4];
#pragma unroll
            for (int j = 0; j < 4; j++) {
                float xs = (j == 0) ? xv.x : (j == 1) ? xv.y : (j == 2) ? xv.z : xv.w;
                const float* wk = Wh + (k4 * 4 + j) * ldw;
#pragma unroll
                for (int c = 0; c < 32; c++) acc[c] = fmaf(xs, wk[c], acc[c]);
            }
        }
    }
    // cross-half reduce via LDS (pad 33 to avoid 64-way bank conflicts)
    if (kh) {
#pragma unroll
        for (int c = 0; c < 32; c++) red[rl * 33 + c] = acc[c];
    }
    __syncthreads();
    if (!kh && valid) {
#pragma unroll
        for (int c = 0; c < 32; c++) acc[c] += red[rl * 33 + c];
        if (grp < 2) {
            float d = dis[row];
            float4* bo = (float4*)(bases + (size_t)row * 64 + grp * 32);
#pragma unroll
            for (int c = 0; c < 8; c++)
                bo[c] = make_float4(acc[4*c] * d, acc[4*c+1] * d,
                                    acc[4*c+2] * d, acc[4*c+3] * d);
        } else {
            float4* wo = (float4*)(wcomb + (size_t)row * 32);
#pragma unroll
            for (int c = 0; c < 8; c++)
                wo[c] = make_float4(acc[4*c] + bc[4*c], acc[4*c+1] + bc[4*c+1],
                                    acc[4*c+2] + bc[4*c+2], acc[4*c+3] + bc[4*c+3]);
        }
    }
}

// ---------------- fused: CSR fill (latency-bound) | gemm1 (VALU-bound) ----------------
__global__ __launch_bounds__(256) void k_fill_gemm(
    const int* __restrict__ ei, int* cursor, u16* __restrict__ csr,
    const float* __restrict__ x, const float* __restrict__ Wb,
    const float* __restrict__ Wc, const float* __restrict__ bc,
    const float* __restrict__ dis,
    float* __restrict__ bases, float* __restrict__ wcomb, int n)
{
    __shared__ float red[128 * 33];
    int b = blockIdx.x;
    int tid = threadIdx.x;
    if (b < NB_FILL) {
        int t = b * 256 + tid;
        if (t < EE / 2) {
            int2 rr = *(const int2*)(ei + 2 * t);
            int2 cc = *(const int2*)(ei + EE + 2 * t);
            int p0 = atomicAdd(&cursor[cc.x], 1);
            csr[p0] = (u16)rr.x;
            int p1 = atomicAdd(&cursor[cc.y], 1);
            csr[p1] = (u16)rr.y;
        }
    } else {
        int bb = b - NB_FILL;
        int grp = bb / NBX;
        int bx = bb - grp * NBX;
        gemm_body(bx, grp, tid, x, Wb, Wc, bc, dis, bases, wcomb, red, n);
    }
}

// ---------------- standalone gemm (layer 2) ----------------
__global__ __launch_bounds__(256) void k_gemm(
    const float* __restrict__ x, const float* __restrict__ Wb,
    const float* __restrict__ Wc, const float* __restrict__ bc,
    const float* __restrict__ dis,
    float* __restrict__ bases, float* __restrict__ wcomb, int n)
{
    __shared__ float red[128 * 33];
    gemm_body(blockIdx.x, blockIdx.y, threadIdx.x, x, Wb, Wc, bc, dis,
              bases, wcomb, red, n);
}

// ---------------- fused aggregate (pipelined u16-CSR float4 gather) + combine ----------------
template<int LAYER2>
__global__ __launch_bounds__(256) void k_agg(
    const u16* __restrict__ csr, const int2* __restrict__ sd,
    const float* __restrict__ bs, const float* __restrict__ dis,
    const float* __restrict__ wcomb, const float* __restrict__ bias,
    float* __restrict__ h,
    const float* __restrict__ Wcls, const float* __restrict__ bcls,
    float* __restrict__ p, int n)
{
    int wid = (blockIdx.x * 256 + threadIdx.x) >> 6;
    int lane = threadIdx.x & 63;
    if (wid >= n) return;
    int2 s2 = sd[wid];
    int start = s2.x, deg = s2.y;
    int g = lane >> 4, q = lane & 15;

    const float4* bs4 = (const float4*)bs;
    float4 acc4 = make_float4(0.f, 0.f, 0.f, 0.f);
    if (g == 0) acc4 = bs4[(size_t)wid * 16 + q];  // self-loop term (pre-scaled)

    // pipelined main loop: 8 edges/iter, next iter's indices prefetched
    int j = 0;
    int ia = 0, ib = 0;
    if (8 <= deg) { ia = csr[start + g]; ib = csr[start + 4 + g]; }
    while (j + 8 <= deg) {
        int jn = j + 8;
        int na = 0, nb = 0;
        if (jn + 8 <= deg) { na = csr[start + jn + g]; nb = csr[start + jn + 4 + g]; }
        float4 v0 = bs4[(size_t)ia * 16 + q];
        float4 v1 = bs4[(size_t)ib * 16 + q];
        acc4.x += v0.x + v1.x;
        acc4.y += v0.y + v1.y;
        acc4.z += v0.z + v1.z;
        acc4.w += v0.w + v1.w;
        ia = na; ib = nb; j = jn;
    }
    // masked tail (<8 left), 4 edges/iter
    int last = start + deg - 1;
    for (; j < deg; j += 4) {
        int idx = start + j + g;
        int r = csr[min(idx, last)];
        float4 v = bs4[(size_t)r * 16 + q];
        float m = (j + g < deg) ? 1.f : 0.f;
        acc4.x = fmaf(v.x, m, acc4.x);
        acc4.y = fmaf(v.y, m, acc4.y);
        acc4.z = fmaf(v.z, m, acc4.z);
        acc4.w = fmaf(v.w, m, acc4.w);
    }

    // reduce across the 4 edge-slots
    acc4.x += __shfl_xor(acc4.x, 16, 64);
    acc4.y += __shfl_xor(acc4.y, 16, 64);
    acc4.z += __shfl_xor(acc4.z, 16, 64);
    acc4.w += __shfl_xor(acc4.w, 16, 64);
    acc4.x += __shfl_xor(acc4.x, 32, 64);
    acc4.y += __shfl_xor(acc4.y, 32, 64);
    acc4.z += __shfl_xor(acc4.z, 32, 64);
    acc4.w += __shfl_xor(acc4.w, 32, 64);

    float d = dis[wid];
    acc4.x *= d; acc4.y *= d; acc4.z *= d; acc4.w *= d;

    // transpose float4-per-lane -> scalar-per-lane: acc = agg[lane]
    int src = lane >> 2;
    float t0 = __shfl(acc4.x, src, 64);
    float t1 = __shfl(acc4.y, src, 64);
    float t2 = __shfl(acc4.z, src, 64);
    float t3 = __shfl(acc4.w, src, 64);
    int c = lane & 3;
    float acc = (c == 0) ? t0 : (c == 1) ? t1 : (c == 2) ? t2 : t3;

    // combine: ch=lane and ch=64+lane
    int fh = lane & 15;
    float a0 = __shfl(acc, fh, 64);
    float a1 = __shfl(acc, 16 + fh, 64);
    float a2 = __shfl(acc, 32 + fh, 64);
    float a3 = __shfl(acc, 48 + fh, 64);
    const float* wn = wcomb + (size_t)wid * 32;
    int hd = lane >> 4;
    float s1 = bias[lane];
    float s2v = bias[64 + lane];
    s1 = fmaf(wn[hd * 4 + 0], a0, s1);
    s1 = fmaf(wn[hd * 4 + 1], a1, s1);
    s1 = fmaf(wn[hd * 4 + 2], a2, s1);
    s1 = fmaf(wn[hd * 4 + 3], a3, s1);
    s2v = fmaf(wn[(4 + hd) * 4 + 0], a0, s2v);
    s2v = fmaf(wn[(4 + hd) * 4 + 1], a1, s2v);
    s2v = fmaf(wn[(4 + hd) * 4 + 2], a2, s2v);
    s2v = fmaf(wn[(4 + hd) * 4 + 3], a3, s2v);

    if (!LAYER2) {
        s1 = fmaxf(s1, 0.f);
        s2v = fmaxf(s2v, 0.f);
        h[(size_t)wid * 128 + lane] = s1;
        h[(size_t)wid * 128 + 64 + lane] = s2v;
    } else {
        float r0 = s1 * Wcls[lane * 2 + 0] + s2v * Wcls[(64 + lane) * 2 + 0];
        float r1 = s1 * Wcls[lane * 2 + 1] + s2v * Wcls[(64 + lane) * 2 + 1];
        float r2 = s1 * Wcls[(128 + lane) * 2 + 0] + s2v * Wcls[(192 + lane) * 2 + 0];
        float r3 = s1 * Wcls[(128 + lane) * 2 + 1] + s2v * Wcls[(192 + lane) * 2 + 1];
#pragma unroll
        for (int off = 32; off; off >>= 1) {
            r0 += __shfl_xor(r0, off, 64);
            r1 += __shfl_xor(r1, off, 64);
            r2 += __shfl_xor(r2, off, 64);
            r3 += __shfl_xor(r3, off, 64);
        }
        if (lane == 0) {
            p[wid * 4 + 0] = r0 + bcls[0];
            p[wid * 4 + 1] = r1 + bcls[1];
            p[wid * 4 + 2] = r2;
            p[wid * 4 + 3] = r3;
        }
    }
}

// ---------------- edge output: 2 edges/thread ----------------
__global__ void k_edge(const int* __restrict__ ei, const float* __restrict__ p,
                       float* __restrict__ out)
{
    int t = blockIdx.x * blockDim.x + threadIdx.x;
    if (t >= EE / 2) return;
    int2 rr = *(const int2*)(ei + 2 * t);
    int2 cc = *(const int2*)(ei + EE + 2 * t);
    float2 pt0 = *(const float2*)(p + rr.x * 4);
    float2 pt1 = *(const float2*)(p + rr.y * 4);
    float2 pb0 = *(const float2*)(p + cc.x * 4 + 2);
    float2 pb1 = *(const float2*)(p + cc.y * 4 + 2);
    float4 o;
    o.x = pt0.x + pb0.x;
    o.y = pt0.y + pb0.y;
    o.z = pt1.x + pb1.x;
    o.w = pt1.y + pb1.y;
    *(float4*)(out + (size_t)t * 4) = o;
}

extern "C" void kernel_launch(void* const* d_in, const int* in_sizes, int n_in,
                              void* d_out, int out_size, void* d_ws, size_t ws_size,
                              hipStream_t stream) {
    const float* x    = (const float*)d_in[0];
    const int*   ei   = (const int*)d_in[1];
    const float* Wb1  = (const float*)d_in[2];
    const float* Wc1  = (const float*)d_in[3];
    const float* bc1  = (const float*)d_in[4];
    const float* b1   = (const float*)d_in[5];
    const float* Wb2  = (const float*)d_in[6];
    const float* Wc2  = (const float*)d_in[7];
    const float* bc2  = (const float*)d_in[8];
    const float* b2   = (const float*)d_in[9];
    const float* Wcls = (const float*)d_in[10];
    const float* bcls = (const float*)d_in[11];
    float* out = (float*)d_out;

    char* ws = (char*)d_ws;
    size_t off = 0;
    auto alloc = [&](size_t bytes) {
        void* pp = ws + off;
        off += (bytes + 15) & ~(size_t)15;  // 16B-align every region
        return pp;
    };

    float* dis    = (float*)alloc(50048 * 4);
    float* bases  = (float*)alloc((size_t)NN * 64 * 4);
    float* wcomb  = (float*)alloc((size_t)NN * 32 * 4);
    float* h      = (float*)alloc((size_t)NN * 128 * 4);
    float* p      = (float*)alloc((size_t)NN * 4 * 4);
    int*   cnt    = (int*)alloc(50048 * 4);
    int*   sloc   = (int*)alloc(50048 * 4);
    int*   cursor = (int*)alloc(50048 * 4);
    int*   bsum   = (int*)alloc(256 * 4);
    int2*  sd     = (int2*)alloc((size_t)50048 * 8);
    u16*   csr    = (u16*)alloc((size_t)EE * 2);

    const int B = 256;
    int gN   = (NN + B - 1) / B;   // 196
    int gN64 = (NN * 64) / B;      // 12500
    dim3 gG(NBX, 3);

    // CSR build prep
    hipMemsetAsync(cnt, 0, NN * sizeof(int), stream);
    k_count<<<NB_FILL, B, 0, stream>>>(ei, cnt);
    k_scan1<<<gN, B, 0, stream>>>(cnt, sloc, bsum, dis, NN);
    k_scan23<<<gN, B, 0, stream>>>(sloc, bsum, cnt, sd, cursor, NN, gN);

    // fused: CSR fill | conv1 gemm (independent; fill latency hides under gemm VALU)
    k_fill_gemm<<<NB_FILL + NBX * 3, B, 0, stream>>>(
        ei, cursor, csr, x, Wb1, Wc1, bc1, dis, bases, wcomb, NN);
    k_agg<0><<<gN64, B, 0, stream>>>(csr, sd, bases, dis, wcomb, b1, h,
                                     Wcls, bcls, p, NN);

    // conv2 (+ fused edge-cls projection)
    k_gemm<<<gG, B, 0, stream>>>(h, Wb2, Wc2, bc2, dis, bases, wcomb, NN);
    k_agg<1><<<gN64, B, 0, stream>>>(csr, sd, bases, dis, wcomb, b2, h,
                                     Wcls, bcls, p, NN);

    // edge output
    k_edge<<<NB_FILL, B, 0, stream>>>(ei, p, out);
}

// Round 5
// 448.339 us; speedup vs baseline: 1.0122x; 1.0122x over previous
//
#include <hip/hip_runtime.h>
#include <hip/hip_fp16.h>

#define NN 50000
#define EE 800000
#define NBX 391          // ceil(50000/128) row-blocks for gemm
#define NB_E2 1563       // ceil(400000/256): 2 edges/thread grids

// ---------------- degree count (2 edges/thread) ----------------
__global__ void k_count(const int* __restrict__ ei, int* cnt) {
    int t = blockIdx.x * 256 + threadIdx.x;
    if (t < EE / 2) {
        int2 cc = *(const int2*)(ei + EE + 2 * t);
        atomicAdd(&cnt[cc.x], 1);
        atomicAdd(&cnt[cc.y], 1);
    }
}

// ---------------- scan pass 1: per-block exclusive scan + dis ----------------
__global__ void k_scan1(const int* __restrict__ cnt, int* sloc, int* bsum,
                        float* dis, int n) {
    __shared__ int s[256];
    int tid = threadIdx.x;
    int i = blockIdx.x * 256 + tid;
    int v = (i < n) ? cnt[i] : 0;
    if (i < n) dis[i] = rsqrtf((float)v + 1.0f);  // +1 self loop
    s[tid] = v;
    __syncthreads();
    for (int off = 1; off < 256; off <<= 1) {
        int t2 = 0;
        if (tid >= off) t2 = s[tid - off];
        __syncthreads();
        if (tid >= off) s[tid] += t2;
        __syncthreads();
    }
    if (i < n) sloc[i] = s[tid] - v;
    if (tid == 255) bsum[blockIdx.x] = s[255];
}

// ---------------- scan pass 2+3 fused ----------------
__global__ void k_scan23(const int* __restrict__ sloc, const int* __restrict__ bsum,
                         const int* __restrict__ cnt, int2* sd, int* cursor,
                         int n, int nb) {
    __shared__ int sb[256];
    int tid = threadIdx.x, b = blockIdx.x;
    int v = (tid < nb && tid < b) ? bsum[tid] : 0;
    sb[tid] = v;
    __syncthreads();
    for (int off = 128; off; off >>= 1) {
        if (tid < off) sb[tid] += sb[tid + off];
        __syncthreads();
    }
    int boff = sb[0];
    int i = b * 256 + tid;
    if (i < n) {
        int st = sloc[i] + boff;
        sd[i] = make_int2(st, cnt[i]);
        cursor[i] = st;
    }
}

// ---------------- CSR fill: int32 stores (dword scatter — no RMW), 2 edges/thread ----------------
__global__ void k_fill(const int* __restrict__ ei, int* cursor, int* __restrict__ csr) {
    int t = blockIdx.x * 256 + threadIdx.x;
    if (t < EE / 2) {
        int2 rr = *(const int2*)(ei + 2 * t);
        int2 cc = *(const int2*)(ei + EE + 2 * t);
        int p0 = atomicAdd(&cursor[cc.x], 1);
        csr[p0] = rr.x;
        int p1 = atomicAdd(&cursor[cc.y], 1);
        csr[p1] = rr.y;
    }
}

// ---------------- GEMM: K-split x2, LDS reduce; grp 0,1 -> bases*dis (fp16) ; 2 -> wcomb (f32) ----------------
__global__ __launch_bounds__(256) void k_gemm(
    const float* __restrict__ x, const float* __restrict__ Wb,
    const float* __restrict__ Wc, const float* __restrict__ bc,
    const float* __restrict__ dis,
    __half* __restrict__ bsh, float* __restrict__ wcomb, int n)
{
    __shared__ float red[128 * 33];
    int bx = blockIdx.x, grp = blockIdx.y, tid = threadIdx.x;
    int rl = tid & 127, kh = tid >> 7;
    int row = bx * 128 + rl;
    bool valid = row < n;
    float acc[32];
#pragma unroll
    for (int c = 0; c < 32; c++) acc[c] = 0.f;

    const float* W = (grp < 2) ? (Wb + grp * 32) : Wc;
    int ldw = (grp < 2) ? 64 : 32;
    const float* Wh = W + kh * 64 * ldw;

    if (valid) {
        const float4* xr = (const float4*)(x + (size_t)row * 128 + kh * 64);
        for (int k4 = 0; k4 < 16; k4++) {
            float4 xv = xr[k4];
#pragma unroll
            for (int j = 0; j < 4; j++) {
                float xs = (j == 0) ? xv.x : (j == 1) ? xv.y : (j == 2) ? xv.z : xv.w;
                const float* wk = Wh + (k4 * 4 + j) * ldw;
#pragma unroll
                for (int c = 0; c < 32; c++) acc[c] = fmaf(xs, wk[c], acc[c]);
            }
        }
    }
    if (kh) {
#pragma unroll
        for (int c = 0; c < 32; c++) red[rl * 33 + c] = acc[c];
    }
    __syncthreads();
    if (!kh && valid) {
#pragma unroll
        for (int c = 0; c < 32; c++) acc[c] += red[rl * 33 + c];
        if (grp < 2) {
            float d = dis[row];
            __half2 hh[16];
#pragma unroll
            for (int c = 0; c < 16; c++)
                hh[c] = __floats2half2_rn(acc[2 * c] * d, acc[2 * c + 1] * d);
            uint4* bo = (uint4*)(bsh + (size_t)row * 64 + grp * 32);
            const uint4* src = (const uint4*)hh;
#pragma unroll
            for (int c = 0; c < 4; c++) bo[c] = src[c];
        } else {
            float4* wo = (float4*)(wcomb + (size_t)row * 32);
#pragma unroll
            for (int c = 0; c < 8; c++)
                wo[c] = make_float4(acc[4*c] + bc[4*c], acc[4*c+1] + bc[4*c+1],
                                    acc[4*c+2] + bc[4*c+2], acc[4*c+3] + bc[4*c+3]);
        }
    }
}

// ---------------- fused aggregate (fp16 gather, pipelined, 8 edges/iter) + combine ----------------
// lane = 4 edge-slots (g=lane>>4) x 16 feature-quads (q=lane&15); 8B/lane = full 128B row per slot
template<int LAYER2>
__global__ __launch_bounds__(256) void k_agg(
    const int* __restrict__ csr, const int2* __restrict__ sd,
    const __half* __restrict__ bsh, const float* __restrict__ dis,
    const float* __restrict__ wcomb, const float* __restrict__ bias,
    float* __restrict__ h,
    const float* __restrict__ Wcls, const float* __restrict__ bcls,
    float* __restrict__ p, int n)
{
    int wid = (blockIdx.x * 256 + threadIdx.x) >> 6;
    int lane = threadIdx.x & 63;
    if (wid >= n) return;
    int2 s2 = sd[wid];
    int start = s2.x, deg = s2.y;
    int g = lane >> 4, q = lane & 15;

    const uint2* bsp = (const uint2*)bsh;  // 8B = 4 halfs; row stride = 16 uint2
    float4 acc4 = make_float4(0.f, 0.f, 0.f, 0.f);
    if (g == 0) {  // self-loop term (pre-scaled)
        uint2 v = bsp[(size_t)wid * 16 + q];
        float2 lo = __half22float2(*(const __half2*)&v.x);
        float2 hi = __half22float2(*(const __half2*)&v.y);
        acc4 = make_float4(lo.x, lo.y, hi.x, hi.y);
    }

    // pipelined main loop: 8 edges/iter, next iter's indices prefetched
    int j = 0;
    int ia = 0, ib = 0;
    if (8 <= deg) { ia = csr[start + g]; ib = csr[start + 4 + g]; }
    while (j + 8 <= deg) {
        int jn = j + 8;
        int na = 0, nb = 0;
        if (jn + 8 <= deg) { na = csr[start + jn + g]; nb = csr[start + jn + 4 + g]; }
        uint2 v0 = bsp[(size_t)ia * 16 + q];
        uint2 v1 = bsp[(size_t)ib * 16 + q];
        float2 l0 = __half22float2(*(const __half2*)&v0.x);
        float2 h0 = __half22float2(*(const __half2*)&v0.y);
        float2 l1 = __half22float2(*(const __half2*)&v1.x);
        float2 h1 = __half22float2(*(const __half2*)&v1.y);
        acc4.x += l0.x + l1.x;
        acc4.y += l0.y + l1.y;
        acc4.z += h0.x + h1.x;
        acc4.w += h0.y + h1.y;
        ia = na; ib = nb; j = jn;
    }
    // masked tail (<8 left), 4 edges/iter
    int last = start + deg - 1;
    for (; j < deg; j += 4) {
        int idx = start + j + g;
        int r = csr[min(idx, last)];
        uint2 v = bsp[(size_t)r * 16 + q];
        float2 lo = __half22float2(*(const __half2*)&v.x);
        float2 hi = __half22float2(*(const __half2*)&v.y);
        float m = (j + g < deg) ? 1.f : 0.f;
        acc4.x = fmaf(lo.x, m, acc4.x);
        acc4.y = fmaf(lo.y, m, acc4.y);
        acc4.z = fmaf(hi.x, m, acc4.z);
        acc4.w = fmaf(hi.y, m, acc4.w);
    }

    // reduce across the 4 edge-slots
    acc4.x += __shfl_xor(acc4.x, 16, 64);
    acc4.y += __shfl_xor(acc4.y, 16, 64);
    acc4.z += __shfl_xor(acc4.z, 16, 64);
    acc4.w += __shfl_xor(acc4.w, 16, 64);
    acc4.x += __shfl_xor(acc4.x, 32, 64);
    acc4.y += __shfl_xor(acc4.y, 32, 64);
    acc4.z += __shfl_xor(acc4.z, 32, 64);
    acc4.w += __shfl_xor(acc4.w, 32, 64);

    float d = dis[wid];
    acc4.x *= d; acc4.y *= d; acc4.z *= d; acc4.w *= d;

    // transpose float4-per-lane -> scalar-per-lane: acc = agg[lane]
    int src = lane >> 2;
    float t0 = __shfl(acc4.x, src, 64);
    float t1 = __shfl(acc4.y, src, 64);
    float t2 = __shfl(acc4.z, src, 64);
    float t3 = __shfl(acc4.w, src, 64);
    int c = lane & 3;
    float acc = (c == 0) ? t0 : (c == 1) ? t1 : (c == 2) ? t2 : t3;

    // combine: ch=lane and ch=64+lane
    int fh = lane & 15;
    float a0 = __shfl(acc, fh, 64);
    float a1 = __shfl(acc, 16 + fh, 64);
    float a2 = __shfl(acc, 32 + fh, 64);
    float a3 = __shfl(acc, 48 + fh, 64);
    const float* wn = wcomb + (size_t)wid * 32;
    int hd = lane >> 4;
    float s1 = bias[lane];
    float s2v = bias[64 + lane];
    s1 = fmaf(wn[hd * 4 + 0], a0, s1);
    s1 = fmaf(wn[hd * 4 + 1], a1, s1);
    s1 = fmaf(wn[hd * 4 + 2], a2, s1);
    s1 = fmaf(wn[hd * 4 + 3], a3, s1);
    s2v = fmaf(wn[(4 + hd) * 4 + 0], a0, s2v);
    s2v = fmaf(wn[(4 + hd) * 4 + 1], a1, s2v);
    s2v = fmaf(wn[(4 + hd) * 4 + 2], a2, s2v);
    s2v = fmaf(wn[(4 + hd) * 4 + 3], a3, s2v);

    if (!LAYER2) {
        s1 = fmaxf(s1, 0.f);
        s2v = fmaxf(s2v, 0.f);
        h[(size_t)wid * 128 + lane] = s1;
        h[(size_t)wid * 128 + 64 + lane] = s2v;
    } else {
        float r0 = s1 * Wcls[lane * 2 + 0] + s2v * Wcls[(64 + lane) * 2 + 0];
        float r1 = s1 * Wcls[lane * 2 + 1] + s2v * Wcls[(64 + lane) * 2 + 1];
        float r2 = s1 * Wcls[(128 + lane) * 2 + 0] + s2v * Wcls[(192 + lane) * 2 + 0];
        float r3 = s1 * Wcls[(128 + lane) * 2 + 1] + s2v * Wcls[(192 + lane) * 2 + 1];
#pragma unroll
        for (int off = 32; off; off >>= 1) {
            r0 += __shfl_xor(r0, off, 64);
            r1 += __shfl_xor(r1, off, 64);
            r2 += __shfl_xor(r2, off, 64);
            r3 += __shfl_xor(r3, off, 64);
        }
        if (lane == 0) {
            p[wid * 4 + 0] = r0 + bcls[0];
            p[wid * 4 + 1] = r1 + bcls[1];
            p[wid * 4 + 2] = r2;
            p[wid * 4 + 3] = r3;
        }
    }
}

// ---------------- edge output: 2 edges/thread ----------------
__global__ void k_edge(const int* __restrict__ ei, const float* __restrict__ p,
                       float* __restrict__ out)
{
    int t = blockIdx.x * blockDim.x + threadIdx.x;
    if (t >= EE / 2) return;
    int2 rr = *(const int2*)(ei + 2 * t);
    int2 cc = *(const int2*)(ei + EE + 2 * t);
    float2 pt0 = *(const float2*)(p + rr.x * 4);
    float2 pt1 = *(const float2*)(p + rr.y * 4);
    float2 pb0 = *(const float2*)(p + cc.x * 4 + 2);
    float2 pb1 = *(const float2*)(p + cc.y * 4 + 2);
    float4 o;
    o.x = pt0.x + pb0.x;
    o.y = pt0.y + pb0.y;
    o.z = pt1.x + pb1.x;
    o.w = pt1.y + pb1.y;
    *(float4*)(out + (size_t)t * 4) = o;
}

extern "C" void kernel_launch(void* const* d_in, const int* in_sizes, int n_in,
                              void* d_out, int out_size, void* d_ws, size_t ws_size,
                              hipStream_t stream) {
    const float* x    = (const float*)d_in[0];
    const int*   ei   = (const int*)d_in[1];
    const float* Wb1  = (const float*)d_in[2];
    const float* Wc1  = (const float*)d_in[3];
    const float* bc1  = (const float*)d_in[4];
    const float* b1   = (const float*)d_in[5];
    const float* Wb2  = (const float*)d_in[6];
    const float* Wc2  = (const float*)d_in[7];
    const float* bc2  = (const float*)d_in[8];
    const float* b2   = (const float*)d_in[9];
    const float* Wcls = (const float*)d_in[10];
    const float* bcls = (const float*)d_in[11];
    float* out = (float*)d_out;

    char* ws = (char*)d_ws;
    size_t off = 0;
    auto alloc = [&](size_t bytes) {
        void* pp = ws + off;
        off += (bytes + 15) & ~(size_t)15;
        return pp;
    };

    float*  dis    = (float*)alloc(50048 * 4);
    __half* bsh    = (__half*)alloc((size_t)NN * 64 * 2);
    float*  wcomb  = (float*)alloc((size_t)NN * 32 * 4);
    float*  h      = (float*)alloc((size_t)NN * 128 * 4);
    float*  p      = (float*)alloc((size_t)NN * 4 * 4);
    int*    cnt    = (int*)alloc(50048 * 4);
    int*    sloc   = (int*)alloc(50048 * 4);
    int*    cursor = (int*)alloc(50048 * 4);
    int*    bsum   = (int*)alloc(256 * 4);
    int2*   sd     = (int2*)alloc((size_t)50048 * 8);
    int*    csr    = (int*)alloc((size_t)EE * 4);

    const int B = 256;
    int gN   = (NN + B - 1) / B;   // 196
    int gN64 = (NN * 64) / B;      // 12500
    dim3 gG(NBX, 3);

    // CSR build (shared by both layers)
    hipMemsetAsync(cnt, 0, NN * sizeof(int), stream);
    k_count<<<NB_E2, B, 0, stream>>>(ei, cnt);
    k_scan1<<<gN, B, 0, stream>>>(cnt, sloc, bsum, dis, NN);
    k_scan23<<<gN, B, 0, stream>>>(sloc, bsum, cnt, sd, cursor, NN, gN);
    k_fill<<<NB_E2, B, 0, stream>>>(ei, cursor, csr);

    // conv1
    k_gemm<<<gG, B, 0, stream>>>(x, Wb1, Wc1, bc1, dis, bsh, wcomb, NN);
    k_agg<0><<<gN64, B, 0, stream>>>(csr, sd, bsh, dis, wcomb, b1, h,
                                     Wcls, bcls, p, NN);

    // conv2 (+ fused edge-cls projection)
    k_gemm<<<gG, B, 0, stream>>>(h, Wb2, Wc2, bc2, dis, bsh, wcomb, NN);
    k_agg<1><<<gN64, B, 0, stream>>>(csr, sd, bsh, dis, wcomb, b2, h,
                                     Wcls, bcls, p, NN);

    // edge output
    k_edge<<<NB_E2, B, 0, stream>>>(ei, p, out);
}

// Round 6
// 308.470 us; speedup vs baseline: 1.4712x; 1.4534x over previous
//
#include <hip/hip_runtime.h>
#include <hip/hip_fp16.h>

#define NN 50000
#define EE 800000
#define NB_E2 1563       // ceil(400000/256): 2 edges/thread grids

// ---------------- degree count (2 edges/thread) ----------------
__global__ void k_count(const int* __restrict__ ei, int* cnt) {
    int t = blockIdx.x * 256 + threadIdx.x;
    if (t < EE / 2) {
        int2 cc = *(const int2*)(ei + EE + 2 * t);
        atomicAdd(&cnt[cc.x], 1);
        atomicAdd(&cnt[cc.y], 1);
    }
}

// ---------------- scan pass 1: per-block exclusive scan + dis ----------------
__global__ void k_scan1(const int* __restrict__ cnt, int* sloc, int* bsum,
                        float* dis, int n) {
    __shared__ int s[256];
    int tid = threadIdx.x;
    int i = blockIdx.x * 256 + tid;
    int v = (i < n) ? cnt[i] : 0;
    if (i < n) dis[i] = rsqrtf((float)v + 1.0f);  // +1 self loop
    s[tid] = v;
    __syncthreads();
    for (int off = 1; off < 256; off <<= 1) {
        int t2 = 0;
        if (tid >= off) t2 = s[tid - off];
        __syncthreads();
        if (tid >= off) s[tid] += t2;
        __syncthreads();
    }
    if (i < n) sloc[i] = s[tid] - v;
    if (tid == 255) bsum[blockIdx.x] = s[255];
}

// ---------------- scan pass 2+3 fused ----------------
__global__ void k_scan23(const int* __restrict__ sloc, const int* __restrict__ bsum,
                         const int* __restrict__ cnt, int2* sd, int* cursor,
                         int n, int nb) {
    __shared__ int sb[256];
    int tid = threadIdx.x, b = blockIdx.x;
    int v = (tid < nb && tid < b) ? bsum[tid] : 0;
    sb[tid] = v;
    __syncthreads();
    for (int off = 128; off; off >>= 1) {
        if (tid < off) sb[tid] += sb[tid + off];
        __syncthreads();
    }
    int boff = sb[0];
    int i = b * 256 + tid;
    if (i < n) {
        int st = sloc[i] + boff;
        sd[i] = make_int2(st, cnt[i]);
        cursor[i] = st;
    }
}

// ---------------- CSR fill: int32 dword scatter (no sub-dword RMW!) ----------------
__global__ void k_fill(const int* __restrict__ ei, int* cursor, int* __restrict__ csr) {
    int t = blockIdx.x * 256 + threadIdx.x;
    if (t < EE / 2) {
        int2 rr = *(const int2*)(ei + 2 * t);
        int2 cc = *(const int2*)(ei + EE + 2 * t);
        int p0 = atomicAdd(&cursor[cc.x], 1);
        csr[p0] = rr.x;
        int p1 = atomicAdd(&cursor[cc.y], 1);
        csr[p1] = rr.y;
    }
}

// ---------------- GEMM: LDS-staged x, thread-per-row, W via scalar cache ----------------
// grid (196, 3): grp 0,1 -> bases*dis (fp16 cols grp*32..+31); grp 2 -> wcomb (f32)
// W pointer depends ONLY on blockIdx.y + loop constants -> s_load scalarization.
__global__ __launch_bounds__(256) void k_gemm(
    const float* __restrict__ x, const float* __restrict__ Wb,
    const float* __restrict__ Wc, const float* __restrict__ bc,
    const float* __restrict__ dis,
    __half* __restrict__ bsh, float* __restrict__ wcomb, int n)
{
    __shared__ float xt[32 * 257];  // transposed tile: xt[k][row], stride 257 (conflict-free)
    int tid = threadIdx.x;
    int grp = blockIdx.y;
    int row0 = blockIdx.x * 256;
    int row = row0 + tid;
    bool valid = row < n;

    const float* W = (grp < 2) ? (Wb + grp * 32) : Wc;
    const int ldw = (grp < 2) ? 64 : 32;

    float acc[32];
#pragma unroll
    for (int c = 0; c < 32; c++) acc[c] = 0.f;

    for (int s = 0; s < 4; s++) {
        int base_k = s * 32;
        // coalesced global load: 256 rows x 32 k, full 64B-line use
        float4 v[8];
#pragma unroll
        for (int i = 0; i < 8; i++) {
            int idx = i * 256 + tid;
            int r = idx >> 3;      // 0..255
            int k4 = idx & 7;      // 0..7
            int gr = row0 + r;
            v[i] = (gr < n) ? *(const float4*)(x + (size_t)gr * 128 + base_k + k4 * 4)
                            : make_float4(0.f, 0.f, 0.f, 0.f);
        }
        __syncthreads();  // previous stage fully consumed
#pragma unroll
        for (int i = 0; i < 8; i++) {
            int idx = i * 256 + tid;
            int r = idx >> 3;
            int k4 = idx & 7;
            xt[(k4 * 4 + 0) * 257 + r] = v[i].x;
            xt[(k4 * 4 + 1) * 257 + r] = v[i].y;
            xt[(k4 * 4 + 2) * 257 + r] = v[i].z;
            xt[(k4 * 4 + 3) * 257 + r] = v[i].w;
        }
        __syncthreads();

        const float* Ws = W + base_k * ldw;
#pragma unroll 8
        for (int k = 0; k < 32; k++) {
            float xs = xt[k * 257 + tid];
            const float* wk = Ws + k * ldw;
#pragma unroll
            for (int c = 0; c < 32; c++) acc[c] = fmaf(xs, wk[c], acc[c]);
        }
    }

    if (!valid) return;
    if (grp < 2) {
        float d = dis[row];
        __half2 hh[16];
#pragma unroll
        for (int c = 0; c < 16; c++)
            hh[c] = __floats2half2_rn(acc[2 * c] * d, acc[2 * c + 1] * d);
        uint4* bo = (uint4*)(bsh + (size_t)row * 64 + grp * 32);
        const uint4* src = (const uint4*)hh;
#pragma unroll
        for (int c = 0; c < 4; c++) bo[c] = src[c];
    } else {
        float4* wo = (float4*)(wcomb + (size_t)row * 32);
#pragma unroll
        for (int c = 0; c < 8; c++)
            wo[c] = make_float4(acc[4*c] + bc[4*c], acc[4*c+1] + bc[4*c+1],
                                acc[4*c+2] + bc[4*c+2], acc[4*c+3] + bc[4*c+3]);
    }
}

// ---------------- fused aggregate (fp16 gather, pipelined, 8 edges/iter) + combine ----------------
template<int LAYER2>
__global__ __launch_bounds__(256) void k_agg(
    const int* __restrict__ csr, const int2* __restrict__ sd,
    const __half* __restrict__ bsh, const float* __restrict__ dis,
    const float* __restrict__ wcomb, const float* __restrict__ bias,
    float* __restrict__ h,
    const float* __restrict__ Wcls, const float* __restrict__ bcls,
    float* __restrict__ p, int n)
{
    int wid = (blockIdx.x * 256 + threadIdx.x) >> 6;
    int lane = threadIdx.x & 63;
    if (wid >= n) return;
    int2 s2 = sd[wid];
    int start = s2.x, deg = s2.y;
    int g = lane >> 4, q = lane & 15;

    const uint2* bsp = (const uint2*)bsh;  // 8B = 4 halfs; row stride = 16 uint2
    float4 acc4 = make_float4(0.f, 0.f, 0.f, 0.f);
    if (g == 0) {  // self-loop term (pre-scaled)
        uint2 v = bsp[(size_t)wid * 16 + q];
        float2 lo = __half22float2(*(const __half2*)&v.x);
        float2 hi = __half22float2(*(const __half2*)&v.y);
        acc4 = make_float4(lo.x, lo.y, hi.x, hi.y);
    }

    int j = 0;
    int ia = 0, ib = 0;
    if (8 <= deg) { ia = csr[start + g]; ib = csr[start + 4 + g]; }
    while (j + 8 <= deg) {
        int jn = j + 8;
        int na = 0, nb = 0;
        if (jn + 8 <= deg) { na = csr[start + jn + g]; nb = csr[start + jn + 4 + g]; }
        uint2 v0 = bsp[(size_t)ia * 16 + q];
        uint2 v1 = bsp[(size_t)ib * 16 + q];
        float2 l0 = __half22float2(*(const __half2*)&v0.x);
        float2 h0 = __half22float2(*(const __half2*)&v0.y);
        float2 l1 = __half22float2(*(const __half2*)&v1.x);
        float2 h1 = __half22float2(*(const __half2*)&v1.y);
        acc4.x += l0.x + l1.x;
        acc4.y += l0.y + l1.y;
        acc4.z += h0.x + h1.x;
        acc4.w += h0.y + h1.y;
        ia = na; ib = nb; j = jn;
    }
    int last = start + deg - 1;
    for (; j < deg; j += 4) {
        int idx = start + j + g;
        int r = csr[min(idx, last)];
        uint2 v = bsp[(size_t)r * 16 + q];
        float2 lo = __half22float2(*(const __half2*)&v.x);
        float2 hi = __half22float2(*(const __half2*)&v.y);
        float m = (j + g < deg) ? 1.f : 0.f;
        acc4.x = fmaf(lo.x, m, acc4.x);
        acc4.y = fmaf(lo.y, m, acc4.y);
        acc4.z = fmaf(hi.x, m, acc4.z);
        acc4.w = fmaf(hi.y, m, acc4.w);
    }

    acc4.x += __shfl_xor(acc4.x, 16, 64);
    acc4.y += __shfl_xor(acc4.y, 16, 64);
    acc4.z += __shfl_xor(acc4.z, 16, 64);
    acc4.w += __shfl_xor(acc4.w, 16, 64);
    acc4.x += __shfl_xor(acc4.x, 32, 64);
    acc4.y += __shfl_xor(acc4.y, 32, 64);
    acc4.z += __shfl_xor(acc4.z, 32, 64);
    acc4.w += __shfl_xor(acc4.w, 32, 64);

    float d = dis[wid];
    acc4.x *= d; acc4.y *= d; acc4.z *= d; acc4.w *= d;

    int src = lane >> 2;
    float t0 = __shfl(acc4.x, src, 64);
    float t1 = __shfl(acc4.y, src, 64);
    float t2 = __shfl(acc4.z, src, 64);
    float t3 = __shfl(acc4.w, src, 64);
    int c = lane & 3;
    float acc = (c == 0) ? t0 : (c == 1) ? t1 : (c == 2) ? t2 : t3;

    int fh = lane & 15;
    float a0 = __shfl(acc, fh, 64);
    float a1 = __shfl(acc, 16 + fh, 64);
    float a2 = __shfl(acc, 32 + fh, 64);
    float a3 = __shfl(acc, 48 + fh, 64);
    const float* wn = wcomb + (size_t)wid * 32;
    int hd = lane >> 4;
    float s1 = bias[lane];
    float s2v = bias[64 + lane];
    s1 = fmaf(wn[hd * 4 + 0], a0, s1);
    s1 = fmaf(wn[hd * 4 + 1], a1, s1);
    s1 = fmaf(wn[hd * 4 + 2], a2, s1);
    s1 = fmaf(wn[hd * 4 + 3], a3, s1);
    s2v = fmaf(wn[(4 + hd) * 4 + 0], a0, s2v);
    s2v = fmaf(wn[(4 + hd) * 4 + 1], a1, s2v);
    s2v = fmaf(wn[(4 + hd) * 4 + 2], a2, s2v);
    s2v = fmaf(wn[(4 + hd) * 4 + 3], a3, s2v);

    if (!LAYER2) {
        s1 = fmaxf(s1, 0.f);
        s2v = fmaxf(s2v, 0.f);
        h[(size_t)wid * 128 + lane] = s1;
        h[(size_t)wid * 128 + 64 + lane] = s2v;
    } else {
        float r0 = s1 * Wcls[lane * 2 + 0] + s2v * Wcls[(64 + lane) * 2 + 0];
        float r1 = s1 * Wcls[lane * 2 + 1] + s2v * Wcls[(64 + lane) * 2 + 1];
        float r2 = s1 * Wcls[(128 + lane) * 2 + 0] + s2v * Wcls[(192 + lane) * 2 + 0];
        float r3 = s1 * Wcls[(128 + lane) * 2 + 1] + s2v * Wcls[(192 + lane) * 2 + 1];
#pragma unroll
        for (int off = 32; off; off >>= 1) {
            r0 += __shfl_xor(r0, off, 64);
            r1 += __shfl_xor(r1, off, 64);
            r2 += __shfl_xor(r2, off, 64);
            r3 += __shfl_xor(r3, off, 64);
        }
        if (lane == 0) {
            p[wid * 4 + 0] = r0 + bcls[0];
            p[wid * 4 + 1] = r1 + bcls[1];
            p[wid * 4 + 2] = r2;
            p[wid * 4 + 3] = r3;
        }
    }
}

// ---------------- edge output: 2 edges/thread ----------------
__global__ void k_edge(const int* __restrict__ ei, const float* __restrict__ p,
                       float* __restrict__ out)
{
    int t = blockIdx.x * blockDim.x + threadIdx.x;
    if (t >= EE / 2) return;
    int2 rr = *(const int2*)(ei + 2 * t);
    int2 cc = *(const int2*)(ei + EE + 2 * t);
    float2 pt0 = *(const float2*)(p + rr.x * 4);
    float2 pt1 = *(const float2*)(p + rr.y * 4);
    float2 pb0 = *(const float2*)(p + cc.x * 4 + 2);
    float2 pb1 = *(const float2*)(p + cc.y * 4 + 2);
    float4 o;
    o.x = pt0.x + pb0.x;
    o.y = pt0.y + pb0.y;
    o.z = pt1.x + pb1.x;
    o.w = pt1.y + pb1.y;
    *(float4*)(out + (size_t)t * 4) = o;
}

extern "C" void kernel_launch(void* const* d_in, const int* in_sizes, int n_in,
                              void* d_out, int out_size, void* d_ws, size_t ws_size,
                              hipStream_t stream) {
    const float* x    = (const float*)d_in[0];
    const int*   ei   = (const int*)d_in[1];
    const float* Wb1  = (const float*)d_in[2];
    const float* Wc1  = (const float*)d_in[3];
    const float* bc1  = (const float*)d_in[4];
    const float* b1   = (const float*)d_in[5];
    const float* Wb2  = (const float*)d_in[6];
    const float* Wc2  = (const float*)d_in[7];
    const float* bc2  = (const float*)d_in[8];
    const float* b2   = (const float*)d_in[9];
    const float* Wcls = (const float*)d_in[10];
    const float* bcls = (const float*)d_in[11];
    float* out = (float*)d_out;

    char* ws = (char*)d_ws;
    size_t off = 0;
    auto alloc = [&](size_t bytes) {
        void* pp = ws + off;
        off += (bytes + 15) & ~(size_t)15;
        return pp;
    };

    float*  dis    = (float*)alloc(50048 * 4);
    __half* bsh    = (__half*)alloc((size_t)NN * 64 * 2);
    float*  wcomb  = (float*)alloc((size_t)NN * 32 * 4);
    float*  h      = (float*)alloc((size_t)NN * 128 * 4);
    float*  p      = (float*)alloc((size_t)NN * 4 * 4);
    int*    cnt    = (int*)alloc(50048 * 4);
    int*    sloc   = (int*)alloc(50048 * 4);
    int*    cursor = (int*)alloc(50048 * 4);
    int*    bsum   = (int*)alloc(256 * 4);
    int2*   sd     = (int2*)alloc((size_t)50048 * 8);
    int*    csr    = (int*)alloc((size_t)EE * 4);

    const int B = 256;
    int gN   = (NN + B - 1) / B;   // 196
    int gN64 = (NN * 64) / B;      // 12500
    dim3 gG(gN, 3);                // 196 row-blocks x 3 col-groups

    // CSR build (shared by both layers)
    hipMemsetAsync(cnt, 0, NN * sizeof(int), stream);
    k_count<<<NB_E2, B, 0, stream>>>(ei, cnt);
    k_scan1<<<gN, B, 0, stream>>>(cnt, sloc, bsum, dis, NN);
    k_scan23<<<gN, B, 0, stream>>>(sloc, bsum, cnt, sd, cursor, NN, gN);
    k_fill<<<NB_E2, B, 0, stream>>>(ei, cursor, csr);

    // conv1
    k_gemm<<<gG, B, 0, stream>>>(x, Wb1, Wc1, bc1, dis, bsh, wcomb, NN);
    k_agg<0><<<gN64, B, 0, stream>>>(csr, sd, bsh, dis, wcomb, b1, h,
                                     Wcls, bcls, p, NN);

    // conv2 (+ fused edge-cls projection)
    k_gemm<<<gG, B, 0, stream>>>(h, Wb2, Wc2, bc2, dis, bsh, wcomb, NN);
    k_agg<1><<<gN64, B, 0, stream>>>(csr, sd, bsh, dis, wcomb, b2, h,
                                     Wcls, bcls, p, NN);

    // edge output
    k_edge<<<NB_E2, B, 0, stream>>>(ei, p, out);
}

// Round 7
// 277.687 us; speedup vs baseline: 1.6343x; 1.1109x over previous
//
#include <hip/hip_runtime.h>
#include <hip/hip_fp16.h>

#define NN 50000
#define EE 800000
#define NB_E2 1563       // ceil(400000/256): 2 edges/thread grids
#define WIN 6250         // node-window per XCD slot (8 * 6250 = 50000)
#define EPB 1024         // edges per fill chunk (256 thr x 4)
#define NCHUNK 782       // ceil(800000/1024)

// ---------------- degree count + rank (rank = position within col bucket) ----------------
__global__ void k_count(const int* __restrict__ ei, int* cnt, int* __restrict__ rank) {
    int t = blockIdx.x * 256 + threadIdx.x;
    if (t < EE / 2) {
        int2 cc = *(const int2*)(ei + EE + 2 * t);
        int r0 = atomicAdd(&cnt[cc.x], 1);
        int r1 = atomicAdd(&cnt[cc.y], 1);
        *(int2*)(rank + 2 * t) = make_int2(r0, r1);
    }
}

// ---------------- scan pass 1: per-block exclusive scan + dis ----------------
__global__ void k_scan1(const int* __restrict__ cnt, int* sloc, int* bsum,
                        float* dis, int n) {
    __shared__ int s[256];
    int tid = threadIdx.x;
    int i = blockIdx.x * 256 + tid;
    int v = (i < n) ? cnt[i] : 0;
    if (i < n) dis[i] = rsqrtf((float)v + 1.0f);  // +1 self loop
    s[tid] = v;
    __syncthreads();
    for (int off = 1; off < 256; off <<= 1) {
        int t2 = 0;
        if (tid >= off) t2 = s[tid - off];
        __syncthreads();
        if (tid >= off) s[tid] += t2;
        __syncthreads();
    }
    if (i < n) sloc[i] = s[tid] - v;
    if (tid == 255) bsum[blockIdx.x] = s[255];
}

// ---------------- scan pass 2+3 fused: finalize starts + sd ----------------
__global__ void k_scan23(const int* __restrict__ sloc, const int* __restrict__ bsum,
                         const int* __restrict__ cnt, int2* sd, int* starts,
                         int n, int nb) {
    __shared__ int sb[256];
    int tid = threadIdx.x, b = blockIdx.x;
    int v = (tid < nb && tid < b) ? bsum[tid] : 0;
    sb[tid] = v;
    __syncthreads();
    for (int off = 128; off; off >>= 1) {
        if (tid < off) sb[tid] += sb[tid + off];
        __syncthreads();
    }
    int boff = sb[0];
    int i = b * 256 + tid;
    if (i < n) {
        int st = sloc[i] + boff;
        sd[i] = make_int2(st, cnt[i]);
        starts[i] = st;
    }
}

// ---------------- CSR fill: atomic-free, XCD-windowed scatter ----------------
// blockIdx.x = chunk*8 + w. Window w covers cols [w*WIN,(w+1)*WIN): all stores into
// that csr region issue from blocks with blockIdx%8==w -> one XCD's L2 owns it.
__global__ __launch_bounds__(256) void k_fill(
    const int* __restrict__ ei, const int* __restrict__ rank,
    const int* __restrict__ starts, int* __restrict__ csr)
{
    int w = blockIdx.x & 7;
    int chunk = blockIdx.x >> 3;
    int base = chunk * EPB + threadIdx.x * 4;
    int lo = w * WIN, hi = lo + WIN;
    if (base + 3 < EE) {
        int4 rr = *(const int4*)(ei + base);
        int4 cc = *(const int4*)(ei + EE + base);
        int4 rk = *(const int4*)(rank + base);
        if (cc.x >= lo && cc.x < hi) csr[starts[cc.x] + rk.x] = rr.x;
        if (cc.y >= lo && cc.y < hi) csr[starts[cc.y] + rk.y] = rr.y;
        if (cc.z >= lo && cc.z < hi) csr[starts[cc.z] + rk.z] = rr.z;
        if (cc.w >= lo && cc.w < hi) csr[starts[cc.w] + rk.w] = rr.w;
    } else {
        for (int e = 0; e < 4; e++) {
            int t = base + e;
            if (t < EE) {
                int c = ei[EE + t];
                if (c >= lo && c < hi) csr[starts[c] + rank[t]] = ei[t];
            }
        }
    }
}

// ---------------- GEMM: LDS-staged x, thread-per-row, W via scalar cache ----------------
__global__ __launch_bounds__(256) void k_gemm(
    const float* __restrict__ x, const float* __restrict__ Wb,
    const float* __restrict__ Wc, const float* __restrict__ bc,
    const float* __restrict__ dis,
    __half* __restrict__ bsh, float* __restrict__ wcomb, int n)
{
    __shared__ float xt[32 * 257];  // transposed tile: xt[k][row]
    int tid = threadIdx.x;
    int grp = blockIdx.y;
    int row0 = blockIdx.x * 256;
    int row = row0 + tid;
    bool valid = row < n;

    const float* W = (grp < 2) ? (Wb + grp * 32) : Wc;
    const int ldw = (grp < 2) ? 64 : 32;

    float acc[32];
#pragma unroll
    for (int c = 0; c < 32; c++) acc[c] = 0.f;

    for (int s = 0; s < 4; s++) {
        int base_k = s * 32;
        float4 v[8];
#pragma unroll
        for (int i = 0; i < 8; i++) {
            int idx = i * 256 + tid;
            int r = idx >> 3;
            int k4 = idx & 7;
            int gr = row0 + r;
            v[i] = (gr < n) ? *(const float4*)(x + (size_t)gr * 128 + base_k + k4 * 4)
                            : make_float4(0.f, 0.f, 0.f, 0.f);
        }
        __syncthreads();
#pragma unroll
        for (int i = 0; i < 8; i++) {
            int idx = i * 256 + tid;
            int r = idx >> 3;
            int k4 = idx & 7;
            xt[(k4 * 4 + 0) * 257 + r] = v[i].x;
            xt[(k4 * 4 + 1) * 257 + r] = v[i].y;
            xt[(k4 * 4 + 2) * 257 + r] = v[i].z;
            xt[(k4 * 4 + 3) * 257 + r] = v[i].w;
        }
        __syncthreads();

        const float* Ws = W + base_k * ldw;
#pragma unroll 8
        for (int k = 0; k < 32; k++) {
            float xs = xt[k * 257 + tid];
            const float* wk = Ws + k * ldw;
#pragma unroll
            for (int c = 0; c < 32; c++) acc[c] = fmaf(xs, wk[c], acc[c]);
        }
    }

    if (!valid) return;
    if (grp < 2) {
        float d = dis[row];
        __half2 hh[16];
#pragma unroll
        for (int c = 0; c < 16; c++)
            hh[c] = __floats2half2_rn(acc[2 * c] * d, acc[2 * c + 1] * d);
        uint4* bo = (uint4*)(bsh + (size_t)row * 64 + grp * 32);
        const uint4* src = (const uint4*)hh;
#pragma unroll
        for (int c = 0; c < 4; c++) bo[c] = src[c];
    } else {
        float4* wo = (float4*)(wcomb + (size_t)row * 32);
#pragma unroll
        for (int c = 0; c < 8; c++)
            wo[c] = make_float4(acc[4*c] + bc[4*c], acc[4*c+1] + bc[4*c+1],
                                acc[4*c+2] + bc[4*c+2], acc[4*c+3] + bc[4*c+3]);
    }
}

// ---------------- fused aggregate (fp16 gather, pipelined, 8 edges/iter) + combine ----------------
template<int LAYER2>
__global__ __launch_bounds__(256) void k_agg(
    const int* __restrict__ csr, const int2* __restrict__ sd,
    const __half* __restrict__ bsh, const float* __restrict__ dis,
    const float* __restrict__ wcomb, const float* __restrict__ bias,
    float* __restrict__ h,
    const float* __restrict__ Wcls, const float* __restrict__ bcls,
    float* __restrict__ p, int n)
{
    int wid = (blockIdx.x * 256 + threadIdx.x) >> 6;
    int lane = threadIdx.x & 63;
    if (wid >= n) return;
    int2 s2 = sd[wid];
    int start = s2.x, deg = s2.y;
    int g = lane >> 4, q = lane & 15;

    const uint2* bsp = (const uint2*)bsh;
    float4 acc4 = make_float4(0.f, 0.f, 0.f, 0.f);
    if (g == 0) {  // self-loop term (pre-scaled)
        uint2 v = bsp[(size_t)wid * 16 + q];
        float2 lo = __half22float2(*(const __half2*)&v.x);
        float2 hi = __half22float2(*(const __half2*)&v.y);
        acc4 = make_float4(lo.x, lo.y, hi.x, hi.y);
    }

    int j = 0;
    int ia = 0, ib = 0;
    if (8 <= deg) { ia = csr[start + g]; ib = csr[start + 4 + g]; }
    while (j + 8 <= deg) {
        int jn = j + 8;
        int na = 0, nb = 0;
        if (jn + 8 <= deg) { na = csr[start + jn + g]; nb = csr[start + jn + 4 + g]; }
        uint2 v0 = bsp[(size_t)ia * 16 + q];
        uint2 v1 = bsp[(size_t)ib * 16 + q];
        float2 l0 = __half22float2(*(const __half2*)&v0.x);
        float2 h0 = __half22float2(*(const __half2*)&v0.y);
        float2 l1 = __half22float2(*(const __half2*)&v1.x);
        float2 h1 = __half22float2(*(const __half2*)&v1.y);
        acc4.x += l0.x + l1.x;
        acc4.y += l0.y + l1.y;
        acc4.z += h0.x + h1.x;
        acc4.w += h0.y + h1.y;
        ia = na; ib = nb; j = jn;
    }
    int last = start + deg - 1;
    for (; j < deg; j += 4) {
        int idx = start + j + g;
        int r = csr[min(idx, last)];
        uint2 v = bsp[(size_t)r * 16 + q];
        float2 lo = __half22float2(*(const __half2*)&v.x);
        float2 hi = __half22float2(*(const __half2*)&v.y);
        float m = (j + g < deg) ? 1.f : 0.f;
        acc4.x = fmaf(lo.x, m, acc4.x);
        acc4.y = fmaf(lo.y, m, acc4.y);
        acc4.z = fmaf(hi.x, m, acc4.z);
        acc4.w = fmaf(hi.y, m, acc4.w);
    }

    acc4.x += __shfl_xor(acc4.x, 16, 64);
    acc4.y += __shfl_xor(acc4.y, 16, 64);
    acc4.z += __shfl_xor(acc4.z, 16, 64);
    acc4.w += __shfl_xor(acc4.w, 16, 64);
    acc4.x += __shfl_xor(acc4.x, 32, 64);
    acc4.y += __shfl_xor(acc4.y, 32, 64);
    acc4.z += __shfl_xor(acc4.z, 32, 64);
    acc4.w += __shfl_xor(acc4.w, 32, 64);

    float d = dis[wid];
    acc4.x *= d; acc4.y *= d; acc4.z *= d; acc4.w *= d;

    int src = lane >> 2;
    float t0 = __shfl(acc4.x, src, 64);
    float t1 = __shfl(acc4.y, src, 64);
    float t2 = __shfl(acc4.z, src, 64);
    float t3 = __shfl(acc4.w, src, 64);
    int c = lane & 3;
    float acc = (c == 0) ? t0 : (c == 1) ? t1 : (c == 2) ? t2 : t3;

    int fh = lane & 15;
    float a0 = __shfl(acc, fh, 64);
    float a1 = __shfl(acc, 16 + fh, 64);
    float a2 = __shfl(acc, 32 + fh, 64);
    float a3 = __shfl(acc, 48 + fh, 64);
    const float* wn = wcomb + (size_t)wid * 32;
    int hd = lane >> 4;
    float s1 = bias[lane];
    float s2v = bias[64 + lane];
    s1 = fmaf(wn[hd * 4 + 0], a0, s1);
    s1 = fmaf(wn[hd * 4 + 1], a1, s1);
    s1 = fmaf(wn[hd * 4 + 2], a2, s1);
    s1 = fmaf(wn[hd * 4 + 3], a3, s1);
    s2v = fmaf(wn[(4 + hd) * 4 + 0], a0, s2v);
    s2v = fmaf(wn[(4 + hd) * 4 + 1], a1, s2v);
    s2v = fmaf(wn[(4 + hd) * 4 + 2], a2, s2v);
    s2v = fmaf(wn[(4 + hd) * 4 + 3], a3, s2v);

    if (!LAYER2) {
        s1 = fmaxf(s1, 0.f);
        s2v = fmaxf(s2v, 0.f);
        h[(size_t)wid * 128 + lane] = s1;
        h[(size_t)wid * 128 + 64 + lane] = s2v;
    } else {
        float r0 = s1 * Wcls[lane * 2 + 0] + s2v * Wcls[(64 + lane) * 2 + 0];
        float r1 = s1 * Wcls[lane * 2 + 1] + s2v * Wcls[(64 + lane) * 2 + 1];
        float r2 = s1 * Wcls[(128 + lane) * 2 + 0] + s2v * Wcls[(192 + lane) * 2 + 0];
        float r3 = s1 * Wcls[(128 + lane) * 2 + 1] + s2v * Wcls[(192 + lane) * 2 + 1];
#pragma unroll
        for (int off = 32; off; off >>= 1) {
            r0 += __shfl_xor(r0, off, 64);
            r1 += __shfl_xor(r1, off, 64);
            r2 += __shfl_xor(r2, off, 64);
            r3 += __shfl_xor(r3, off, 64);
        }
        if (lane == 0) {
            p[wid * 4 + 0] = r0 + bcls[0];
            p[wid * 4 + 1] = r1 + bcls[1];
            p[wid * 4 + 2] = r2;
            p[wid * 4 + 3] = r3;
        }
    }
}

// ---------------- edge output: 2 edges/thread ----------------
__global__ void k_edge(const int* __restrict__ ei, const float* __restrict__ p,
                       float* __restrict__ out)
{
    int t = blockIdx.x * blockDim.x + threadIdx.x;
    if (t >= EE / 2) return;
    int2 rr = *(const int2*)(ei + 2 * t);
    int2 cc = *(const int2*)(ei + EE + 2 * t);
    float2 pt0 = *(const float2*)(p + rr.x * 4);
    float2 pt1 = *(const float2*)(p + rr.y * 4);
    float2 pb0 = *(const float2*)(p + cc.x * 4 + 2);
    float2 pb1 = *(const float2*)(p + cc.y * 4 + 2);
    float4 o;
    o.x = pt0.x + pb0.x;
    o.y = pt0.y + pb0.y;
    o.z = pt1.x + pb1.x;
    o.w = pt1.y + pb1.y;
    *(float4*)(out + (size_t)t * 4) = o;
}

extern "C" void kernel_launch(void* const* d_in, const int* in_sizes, int n_in,
                              void* d_out, int out_size, void* d_ws, size_t ws_size,
                              hipStream_t stream) {
    const float* x    = (const float*)d_in[0];
    const int*   ei   = (const int*)d_in[1];
    const float* Wb1  = (const float*)d_in[2];
    const float* Wc1  = (const float*)d_in[3];
    const float* bc1  = (const float*)d_in[4];
    const float* b1   = (const float*)d_in[5];
    const float* Wb2  = (const float*)d_in[6];
    const float* Wc2  = (const float*)d_in[7];
    const float* bc2  = (const float*)d_in[8];
    const float* b2   = (const float*)d_in[9];
    const float* Wcls = (const float*)d_in[10];
    const float* bcls = (const float*)d_in[11];
    float* out = (float*)d_out;

    char* ws = (char*)d_ws;
    size_t off = 0;
    auto alloc = [&](size_t bytes) {
        void* pp = ws + off;
        off += (bytes + 15) & ~(size_t)15;
        return pp;
    };

    float*  dis    = (float*)alloc(50048 * 4);
    __half* bsh    = (__half*)alloc((size_t)NN * 64 * 2);
    float*  wcomb  = (float*)alloc((size_t)NN * 32 * 4);
    float*  h      = (float*)alloc((size_t)NN * 128 * 4);
    float*  p      = (float*)alloc((size_t)NN * 4 * 4);
    int*    cnt    = (int*)alloc(50048 * 4);
    int*    sloc   = (int*)alloc(50048 * 4);
    int*    starts = (int*)alloc(50048 * 4);
    int*    bsum   = (int*)alloc(256 * 4);
    int2*   sd     = (int2*)alloc((size_t)50048 * 8);
    int*    csr    = (int*)alloc((size_t)EE * 4);
    int*    rank   = (int*)alloc((size_t)EE * 4);

    const int B = 256;
    int gN   = (NN + B - 1) / B;   // 196
    int gN64 = (NN * 64) / B;      // 12500
    dim3 gG(gN, 3);

    // CSR build (shared by both layers)
    hipMemsetAsync(cnt, 0, NN * sizeof(int), stream);
    k_count<<<NB_E2, B, 0, stream>>>(ei, cnt, rank);
    k_scan1<<<gN, B, 0, stream>>>(cnt, sloc, bsum, dis, NN);
    k_scan23<<<gN, B, 0, stream>>>(sloc, bsum, cnt, sd, starts, NN, gN);
    k_fill<<<NCHUNK * 8, B, 0, stream>>>(ei, rank, starts, csr);

    // conv1
    k_gemm<<<gG, B, 0, stream>>>(x, Wb1, Wc1, bc1, dis, bsh, wcomb, NN);
    k_agg<0><<<gN64, B, 0, stream>>>(csr, sd, bsh, dis, wcomb, b1, h,
                                     Wcls, bcls, p, NN);

    // conv2 (+ fused edge-cls projection)
    k_gemm<<<gG, B, 0, stream>>>(h, Wb2, Wc2, bc2, dis, bsh, wcomb, NN);
    k_agg<1><<<gN64, B, 0, stream>>>(csr, sd, bsh, dis, wcomb, b2, h,
                                     Wcls, bcls, p, NN);

    // edge output
    k_edge<<<NB_E2, B, 0, stream>>>(ei, p, out);
}